// Round 12
// baseline (324.783 us; speedup 1.0000x reference)
//
#include <hip/hip_runtime.h>
#include <hip/hip_bf16.h>
#include <math.h>

// Problem constants (fixed by reference)
constexpr int BB = 4;
constexpr int LL = 2048;
constexpr int EE = 512;
constexpr int HH = 8;
constexpr int DD = 64;
constexpr int UU = 40;    // sample count
constexpr int NT = 40;    // n_top
constexpr int NCH = 32;   // key chunks (64 keys each) for split-K attention
constexpr int CK = 64;    // keys per chunk
constexpr int MVC = 16;   // L-chunks for meanv stage 1 (128 rows each)
constexpr float NEG_INF = -3.0e38f;

typedef __attribute__((ext_vector_type(8))) short bf8_t;  // 8 bf16 (4 VGPR)
typedef __attribute__((ext_vector_type(4))) float f4_t;   // MFMA C/D frag

// ---------------------------------------------------------------------------
// split helpers: f32 = hi(RNE bf16) + mid(trunc bf16). Bit-identical math to
// the previous rounds (absmax must stay at 2.44e-4).
// ---------------------------------------------------------------------------
__device__ __forceinline__ void split2pair(float x0, float x1, uint& hp, uint& mp)
{
    uint xb0 = __float_as_uint(x0), xb1 = __float_as_uint(x1);
    uint hb0 = xb0 + 0x7fffu + ((xb0 >> 16) & 1u);
    uint hb1 = xb1 + 0x7fffu + ((xb1 >> 16) & 1u);
    hp = __builtin_amdgcn_perm(hb1, hb0, 0x07060302u);            // [h1.hi16|h0.hi16]
    float r0 = x0 - __uint_as_float(hb0 & 0xffff0000u);
    float r1 = x1 - __uint_as_float(hb1 & 0xffff0000u);
    mp = __builtin_amdgcn_perm(__float_as_uint(r1), __float_as_uint(r0), 0x07060302u);
}

__device__ __forceinline__ void gload16(const void* g, void* l)
{
    __builtin_amdgcn_global_load_lds(
        (const __attribute__((address_space(1))) unsigned int*)g,
        (__attribute__((address_space(3))) unsigned int*)l, 16, 0, 0);
}

__device__ __forceinline__ int swz(int row, int c)
{
    return row * 64 + (((c ^ row ^ (row >> 2)) & 3) << 4);
}

// ---------------------------------------------------------------------------
// K0: pre-convert Wq/Wk/Wv (f32 [512][512]) to bf16 hi+mid planes.
// ---------------------------------------------------------------------------
__global__ __launch_bounds__(256) void wconv_kernel(
    const float* __restrict__ Wq, const float* __restrict__ Wk,
    const float* __restrict__ Wv, unsigned short* __restrict__ wcv)
{
    const int gi  = blockIdx.x * 256 + threadIdx.x;   // 0..98303
    const int z   = gi >> 15;                         // 32768 threads per matrix
    const int off = (gi & 32767) * 8;
    const float* W = (z == 0) ? Wq : (z == 1 ? Wk : Wv);
    float x[8];
    *(float4*)(x)     = *(const float4*)(W + off);
    *(float4*)(x + 4) = *(const float4*)(W + off + 4);
    uint hp[4], mp[4];
#pragma unroll
    for (int p = 0; p < 4; p++) split2pair(x[2 * p], x[2 * p + 1], hp[p], mp[p]);
    unsigned short* Wh = wcv + (size_t)z * 524288;
    *(uint4*)(Wh + off)          = make_uint4(hp[0], hp[1], hp[2], hp[3]);
    *(uint4*)(Wh + 262144 + off) = make_uint4(mp[0], mp[1], mp[2], mp[3]);
}

// ---------------------------------------------------------------------------
// K1: fused QKV projection. 128x128x32 tile, 4 waves, 3-product split-bf16
// MFMA. R1 structure (measured 55-57us): 49KB LDS -> 3 blocks/CU. Do not
// re-raise LDS past ~53KB (R2's 64KB variant lost 7us to occupancy).
// ---------------------------------------------------------------------------
__global__ __launch_bounds__(256, 3) void proj_kernel(
    const float* __restrict__ Xq, const float* __restrict__ Xk, const float* __restrict__ Xv,
    const unsigned short* __restrict__ Wcv,
    const float* __restrict__ bq, const float* __restrict__ bk, const float* __restrict__ bv,
    float* __restrict__ Oq, float* __restrict__ Ok, float* __restrict__ Ov)
{
    // XCD-grouped decode: 768 = 8 xcd * 96; same (yi,zi) -> same xcd.
    const int bid = blockIdx.x;
    const int xg  = bid & 7;
    const int s   = bid >> 3;            // 0..95
    const int yz  = xg * 24 + (s >> 2);  // 0..191
    const int zi  = yz >> 6;             // 0..2
    const int yi  = yz & 63;
    const int m0  = yi * 128;
    const int n0  = (s & 3) * 128;

    const float* X; const float* bias; float* O;
    if (zi == 0)      { X = Xq; bias = bq; O = Oq; }
    else if (zi == 1) { X = Xk; bias = bk; O = Ok; }
    else              { X = Xv; bias = bv; O = Ov; }
    const unsigned short* Wh = Wcv + (size_t)zi * 524288;
    const unsigned short* Wm = Wh + 262144;

    __shared__ char ldsmem[49152];
    char* const LA = ldsmem;           // A tile: hi@0, mid@8192 (16KB)
    char* const LB = ldsmem + 16384;   // B tiles: 2 buffers x (hi 8KB + mid 8KB)

    const int tid  = threadIdx.x;
    const int lane = tid & 63;
    const int wave = tid >> 6;

    const int srow  = tid >> 1;
    const int shalf = tid & 1;
    const int w0 = swz(srow, shalf * 2);
    const int w1 = swz(srow, shalf * 2 + 1);
    const float* Aptr = X + (size_t)(m0 + srow) * EE + shalf * 16;

    const int r0 = tid >> 2;
    const int r1 = 64 + r0;
    const int c0 = (tid & 3) ^ ((r0 ^ (r0 >> 2)) & 3);
    const int c1 = (tid & 3) ^ ((r1 ^ (r1 >> 2)) & 3);
    const unsigned short* bh0 = Wh + (size_t)(n0 + r0) * EE + c0 * 8;
    const unsigned short* bh1 = Wh + (size_t)(n0 + r1) * EE + c1 * 8;
    const unsigned short* bm0 = Wm + (size_t)(n0 + r0) * EE + c0 * 8;
    const unsigned short* bm1 = Wm + (size_t)(n0 + r1) * EE + c1 * 8;
    const int ldst = tid * 16;         // linear dest: wave-uniform base + lane*16

    const int rxor = ((((lane >> 4) ^ lane ^ (lane >> 2)) & 3) << 4);
    const int arow = (wave >> 1) * 64 + (lane & 15);
    const int brow = (wave & 1) * 64 + (lane & 15);

    f4_t acc[4][4];
#pragma unroll
    for (int i = 0; i < 4; i++)
#pragma unroll
        for (int j = 0; j < 4; j++) acc[i][j] = (f4_t)0.0f;

    // prologue: A regs + B tile for kt=0 (into buffer 0)
    float fa[16];
#pragma unroll
    for (int q = 0; q < 4; q++)
        *(float4*)(fa + q * 4) = *(const float4*)(Aptr + q * 4);
    gload16(bh0, LB + ldst);
    gload16(bh1, LB + 4096 + ldst);
    gload16(bm0, LB + 8192 + ldst);
    gload16(bm1, LB + 12288 + ldst);

    int parity = 0;
#pragma unroll 2
    for (int kt = 0; kt < EE; kt += 32) {
        uint ahu[8], amu[8];
#pragma unroll
        for (int p = 0; p < 8; p++)
            split2pair(fa[2 * p], fa[2 * p + 1], ahu[p], amu[p]);

        __syncthreads();   // WAR: previous iteration's A-frag reads done
        *(uint4*)(LA +    0 + w0) = make_uint4(ahu[0], ahu[1], ahu[2], ahu[3]);
        *(uint4*)(LA +    0 + w1) = make_uint4(ahu[4], ahu[5], ahu[6], ahu[7]);
        *(uint4*)(LA + 8192 + w0) = make_uint4(amu[0], amu[1], amu[2], amu[3]);
        *(uint4*)(LA + 8192 + w1) = make_uint4(amu[4], amu[5], amu[6], amu[7]);
        __syncthreads();   // A visible; vmcnt(0) drain completes B(kt)

        if (kt + 32 < EE) {
            const int kn = kt + 32;
#pragma unroll
            for (int q = 0; q < 4; q++)
                *(float4*)(fa + q * 4) = *(const float4*)(Aptr + kn + q * 4);
            char* Bn = LB + (parity ^ 1) * 16384;
            gload16(bh0 + kn, Bn + ldst);
            gload16(bh1 + kn, Bn + 4096 + ldst);
            gload16(bm0 + kn, Bn + 8192 + ldst);
            gload16(bm1 + kn, Bn + 12288 + ldst);
        }

        char* const Bb = LB + parity * 16384;
        bf8_t af[4][2];
#pragma unroll
        for (int i = 0; i < 4; i++) {
            const int ro = (arow + i * 16) * 64 + rxor;
            af[i][0] = *(const bf8_t*)(LA +    0 + ro);
            af[i][1] = *(const bf8_t*)(LA + 8192 + ro);
        }
#pragma unroll
        for (int j = 0; j < 4; j++) {
            const int ro = (brow + j * 16) * 64 + rxor;
            bf8_t bh_ = *(const bf8_t*)(Bb +    0 + ro);
            bf8_t bm_ = *(const bf8_t*)(Bb + 8192 + ro);
#pragma unroll
            for (int i = 0; i < 4; i++) {
                f4_t c = acc[i][j];
                c = __builtin_amdgcn_mfma_f32_16x16x32_bf16(af[i][0], bh_, c, 0, 0, 0); // hh
                c = __builtin_amdgcn_mfma_f32_16x16x32_bf16(af[i][0], bm_, c, 0, 0, 0); // hm
                c = __builtin_amdgcn_mfma_f32_16x16x32_bf16(af[i][1], bh_, c, 0, 0, 0); // mh
                acc[i][j] = c;
            }
        }
        parity ^= 1;
    }

#pragma unroll
    for (int j = 0; j < 4; j++) {
        const int n  = n0 + (wave & 1) * 64 + j * 16 + (lane & 15);
        const float bn = bias[n];
        const int h_ = n >> 6, d_ = n & 63;
#pragma unroll
        for (int i = 0; i < 4; i++) {
            const int mb = m0 + (wave >> 1) * 64 + i * 16 + ((lane >> 4) << 2);
#pragma unroll
            for (int r = 0; r < 4; r++) {
                const int m  = mb + r;
                const int b_ = m >> 11;
                const int l_ = m & (LL - 1);
                O[(((size_t)(b_ * HH + h_) * LL + l_) << 6) + d_] = acc[i][j][r] + bn;
            }
        }
    }
}

// ---------------------------------------------------------------------------
// K_A: FUSED measure + meanv_part (R9 decode — best measured config).
// Three measure locality variants (R4/R6/R10) all nulled -> gather cost is
// ordering-insensitive (likely L3-served in all cases). Keep R9's decode.
// Blocks 0..16383: measure. Blocks 16384..16895: meanv stage 1.
// ---------------------------------------------------------------------------
__global__ __launch_bounds__(256) void measure_meanv_kernel(
    const float* __restrict__ q, const float* __restrict__ k,
    const float* __restrict__ v, const int* __restrict__ idx_sample,
    float* __restrict__ M, float* __restrict__ vpart)
{
    __shared__ float red[4][DD];

    if (blockIdx.x < 16384) {
        const int xg = blockIdx.x & 7;
        const int sb = blockIdx.x >> 3;      // 0..2047
        const int bh = xg * 4 + (sb & 3);
        const int lc = sb >> 2;              // 0..511
        int lane = threadIdx.x & 63;
        int wv   = threadIdx.x >> 6;
        int l    = lc * 4 + wv;
        int s8   = lane >> 3;   // sample slot 0..7
        int c    = lane & 7;    // d-chunk 0..7

        const float* qrow = q + ((size_t)bh * LL + l) * DD + c * 8;
        float4 q0 = *(const float4*)(qrow);
        float4 q1 = *(const float4*)(qrow + 4);

        const float* kbase = k + (size_t)bh * LL * DD;
        const int*   irow  = idx_sample + l * UU;

        float mx = NEG_INF, sum = 0.0f;
#pragma unroll
        for (int it = 0; it < UU; it += 8) {
            int ki = irow[it + s8];
            const float* krow = kbase + (size_t)ki * DD + c * 8;
            float4 k0 = *(const float4*)(krow);
            float4 k1 = *(const float4*)(krow + 4);
            float p = q0.x*k0.x + q0.y*k0.y + q0.z*k0.z + q0.w*k0.w
                    + q1.x*k1.x + q1.y*k1.y + q1.z*k1.z + q1.w*k1.w;
            p += __shfl_xor(p, 1, 64);
            p += __shfl_xor(p, 2, 64);
            p += __shfl_xor(p, 4, 64);
            mx = fmaxf(mx, p);
            sum += p;
        }
        mx  = fmaxf(mx, __shfl_xor(mx, 8, 64));
        sum += __shfl_xor(sum, 8, 64);
        mx  = fmaxf(mx, __shfl_xor(mx, 16, 64));
        sum += __shfl_xor(sum, 16, 64);
        mx  = fmaxf(mx, __shfl_xor(mx, 32, 64));
        sum += __shfl_xor(sum, 32, 64);

        if (lane == 0) M[bh * LL + l] = mx - sum * (1.0f / (float)LL);
    } else {
        const int bid2  = blockIdx.x - 16384;   // 0..511
        const int bh    = bid2 & 31;
        const int chunk = bid2 >> 5;
        const int d  = threadIdx.x & 63;
        const int wv = threadIdx.x >> 6;
        const float* base = v + ((size_t)bh * LL + chunk * 128 + wv * 32) * DD + d;
        float acc = 0.0f;
#pragma unroll
        for (int i = 0; i < 32; i++) acc += base[i * DD];
        red[wv][d] = acc;
        __syncthreads();
        if (wv == 0)
            vpart[(size_t)(chunk * 32 + bh) * DD + d]
                = red[0][d] + red[1][d] + red[2][d] + red[3][d];
    }
}

// ---------------------------------------------------------------------------
// K_B: FUSED topk + meanv_comb. Blocks 0..31: top-40. Blocks 32..63: comb.
// ---------------------------------------------------------------------------
__global__ __launch_bounds__(64) void topk_comb_kernel(const float* __restrict__ M,
                                                       const float* __restrict__ vpart,
                                                       int* __restrict__ top,
                                                       float* __restrict__ mean_v)
{
    if (blockIdx.x < 32) {
        const int bh   = blockIdx.x;
        const int lane = threadIdx.x;

        unsigned long long keys[32];
#pragma unroll
        for (int i = 0; i < 32; i++) {
            int idx = i * 64 + lane;
            uint u  = __float_as_uint(M[bh * LL + idx]);
            uint sv = (u & 0x80000000u) ? ~u : (u | 0x80000000u);
            keys[i] = ((unsigned long long)sv << 32) | (uint)(LL - 1 - idx);
        }
        unsigned long long lmax = 0ull;
#pragma unroll
        for (int i = 0; i < 32; i++) lmax = (keys[i] > lmax) ? keys[i] : lmax;

        for (int it = 0; it < NT; it++) {
            unsigned long long g = lmax;
#pragma unroll
            for (int off = 1; off < 64; off <<= 1) {
                unsigned long long o = __shfl_xor(g, off, 64);
                g = (o > g) ? o : g;
            }
            if (lane == 0) top[bh * NT + it] = LL - 1 - (int)(g & 0xffffffffu);
#pragma unroll
            for (int i = 0; i < 32; i++) if (keys[i] == g) keys[i] = 0ull;
            lmax = 0ull;
#pragma unroll
            for (int i = 0; i < 32; i++) lmax = (keys[i] > lmax) ? keys[i] : lmax;
        }
    } else {
        const int bh = blockIdx.x - 32;
        const int d  = threadIdx.x;
        float s = 0.0f;
#pragma unroll
        for (int c = 0; c < MVC; c++) s += vpart[(size_t)(c * 32 + bh) * DD + d];
        mean_v[bh * DD + d] = s * (1.0f / (float)LL);
    }
}

// ---------------------------------------------------------------------------
// K5: flash-style split-K attention partials (R8/R9 body — measured baseline).
// ---------------------------------------------------------------------------
__global__ __launch_bounds__(256) void pv_kernel(const float* __restrict__ q,
                                                 const float* __restrict__ k,
                                                 const float* __restrict__ v,
                                                 const int* __restrict__ top,
                                                 float* __restrict__ mpart,
                                                 float* __restrict__ lpart,
                                                 float* __restrict__ accpart)
{
    const int bh    = blockIdx.x & 31;
    const int chunk = blockIdx.x >> 5;
    const int tid   = threadIdx.x;
    const int lane  = tid & 63, wv = tid >> 6;

    __shared__ alignas(16) float qs[NT][DD];        // 10240 B
    __shared__ alignas(16) float sc[NT][CK + 4];    // 10880 B (row stride 272B = 16-mult)

    for (int i = tid; i < NT * DD / 4; i += 256) {
        int u  = i >> 4;
        int d4 = (i & 15) * 4;
        int l  = top[bh * NT + u];
        *(float4*)&qs[u][d4] = *(const float4*)(q + ((size_t)bh * LL + l) * DD + d4);
    }
    __syncthreads();

    {
        const int key  = tid >> 2;
        const int dseg = tid & 3;
        const float* krow = k + ((size_t)bh * LL + chunk * CK + key) * DD + dseg * 16;
        float4 k0 = *(const float4*)(krow);
        float4 k1 = *(const float4*)(krow + 4);
        float4 k2 = *(const float4*)(krow + 8);
        float4 k3 = *(const float4*)(krow + 12);
#pragma unroll 8
        for (int u = 0; u < NT; u++) {
            const float* qrow = &qs[u][dseg * 16];
            float4 q0 = *(const float4*)(qrow);
            float4 q1 = *(const float4*)(qrow + 4);
            float4 q2 = *(const float4*)(qrow + 8);
            float4 q3 = *(const float4*)(qrow + 12);
            float p = k0.x*q0.x + k0.y*q0.y + k0.z*q0.z + k0.w*q0.w
                    + k1.x*q1.x + k1.y*q1.y + k1.z*q1.z + k1.w*q1.w
                    + k2.x*q2.x + k2.y*q2.y + k2.z*q2.z + k2.w*q2.w
                    + k3.x*q3.x + k3.y*q3.y + k3.z*q3.z + k3.w*q3.w;
            p += __shfl_xor(p, 1, 64);
            p += __shfl_xor(p, 2, 64);
            if (dseg == 0) sc[u][key] = p;
        }
    }
    __syncthreads();

#pragma unroll
    for (int i = 0; i < 10; i++) {
        const int u = wv * 10 + i;
        float val = sc[u][lane];
        float mx = val;
        mx = fmaxf(mx, __shfl_xor(mx, 1, 64));
        mx = fmaxf(mx, __shfl_xor(mx, 2, 64));
        mx = fmaxf(mx, __shfl_xor(mx, 4, 64));
        mx = fmaxf(mx, __shfl_xor(mx, 8, 64));
        mx = fmaxf(mx, __shfl_xor(mx, 16, 64));
        mx = fmaxf(mx, __shfl_xor(mx, 32, 64));
        float e = __expf(val - mx);
        sc[u][lane] = e;
        float s = e;
        s += __shfl_xor(s, 1, 64);
        s += __shfl_xor(s, 2, 64);
        s += __shfl_xor(s, 4, 64);
        s += __shfl_xor(s, 8, 64);
        s += __shfl_xor(s, 16, 64);
        s += __shfl_xor(s, 32, 64);
        if (lane == 0) {
            mpart[(bh * NCH + chunk) * NT + u] = mx;
            lpart[(bh * NCH + chunk) * NT + u] = s;
        }
    }
    __syncthreads();

    {
        float pacc[10];
#pragma unroll
        for (int i = 0; i < 10; i++) pacc[i] = 0.0f;
        const float* vbase = v + ((size_t)bh * LL + chunk * CK) * DD + lane;
#pragma unroll 4
        for (int t = 0; t < CK; t += 4) {
            float v0 = vbase[(size_t)(t + 0) * DD];
            float v1 = vbase[(size_t)(t + 1) * DD];
            float v2 = vbase[(size_t)(t + 2) * DD];
            float v3 = vbase[(size_t)(t + 3) * DD];
#pragma unroll
            for (int i = 0; i < 10; i++) {
                float4 s = *(const float4*)&sc[wv * 10 + i][t];   // wave-uniform b128
                pacc[i] = fmaf(s.x, v0, pacc[i]);
                pacc[i] = fmaf(s.y, v1, pacc[i]);
                pacc[i] = fmaf(s.z, v2, pacc[i]);
                pacc[i] = fmaf(s.w, v3, pacc[i]);
            }
        }
#pragma unroll
        for (int i = 0; i < 10; i++) {
            const int u = wv * 10 + i;
            accpart[(((size_t)(bh * NCH + chunk)) * NT + u) * 64 + lane] = pacc[i];
        }
    }
}

// ---------------------------------------------------------------------------
// K_C: FUSED delta + base. Blocks 0..319: delta (320x256thr, wave=u).
// Blocks 320..831: base GEMV.
// ---------------------------------------------------------------------------
__global__ __launch_bounds__(256) void delta_base_kernel(
    const float* __restrict__ accpart, const float* __restrict__ lpart,
    const float* __restrict__ mpart, const float* __restrict__ mean_v,
    const float* __restrict__ Wo, const float* __restrict__ bo,
    float* __restrict__ delta_ws, float* __restrict__ base)
{
    if (blockIdx.x < 320) {
        const int bh = blockIdx.x / 10;
        const int ug = blockIdx.x % 10;
        const int wv = threadIdx.x >> 6;
        const int u  = ug * 4 + wv;
        const int d  = threadIdx.x & 63;
        const int bhu = bh * NT + u;

        const float* mp = mpart + (size_t)bh * NCH * NT + u;
        const float* lp = lpart + (size_t)bh * NCH * NT + u;
        const float* ap = accpart + ((size_t)bh * NCH * NT + u) * 64 + d;

        float m = NEG_INF;
#pragma unroll
        for (int c = 0; c < NCH; c++) m = fmaxf(m, mp[c * NT]);
        float den = 0.0f, num = 0.0f;
#pragma unroll
        for (int c = 0; c < NCH; c++) {
            float f = __expf(mp[c * NT] - m);
            den += lp[c * NT] * f;
            num += ap[(size_t)c * NT * 64] * f;
        }
        delta_ws[(size_t)bhu * 64 + d] = num / den - mean_v[bh * DD + d];
    } else {
        const int bid2 = blockIdx.x - 320;
        int lane = threadIdx.x & 63, wv = threadIdx.x >> 6;
        int be = bid2 * 4 + wv;
        int b  = be >> 9;
        int e  = be & (EE - 1);
        const float* mrow = mean_v + b * EE;
        const float* wrow = Wo + (size_t)e * EE;
        float acc = 0.0f;
#pragma unroll
        for (int j = 0; j < 8; j++) acc += mrow[lane + j * 64] * wrow[lane + j * 64];
#pragma unroll
        for (int off = 32; off > 0; off >>= 1) acc += __shfl_down(acc, off, 64);
        if (lane == 0) base[be] = acc + bo[e];
    }
}

// ---------------------------------------------------------------------------
// K6b: broadcast base row to all l
// ---------------------------------------------------------------------------
__global__ __launch_bounds__(256) void bcast_kernel(const float* __restrict__ base,
                                                    float* __restrict__ out)
{
    size_t fi = ((size_t)blockIdx.x * 256 + threadIdx.x) * 4;
    int b  = (int)(fi >> 20);
    int e4 = (int)(fi & (EE - 1));
    float4 val = *(const float4*)(base + b * EE + e4);
    *(float4*)(out + fi) = val;
}

// ---------------------------------------------------------------------------
// K6c-2: correction GEMV + scatter. 256 blocks = (ec 0..7) x (bh 0..31).
// ---------------------------------------------------------------------------
__global__ __launch_bounds__(256) void corr2_kernel(const float* __restrict__ delta_ws,
                                                    const int* __restrict__ top,
                                                    const float* __restrict__ Wo,
                                                    float* __restrict__ out)
{
    const int bh  = blockIdx.x & 31;
    const int ec  = blockIdx.x >> 5;     // 0..7
    const int h   = bh & (HH - 1);
    const int b   = bh >> 3;
    const int tid = threadIdx.x;
    const int lane = tid & 63;
    const int wv   = tid >> 6;

    __shared__ alignas(16) float dl[NT][DD];   // 10240 B, b128-aligned rows
    __shared__ int ltab[NT];

    for (int i = tid; i < NT * DD / 4; i += 256) {
        const int u  = i >> 4;
        const int d4 = (i & 15) * 4;
        *(float4*)&dl[u][d4] = *(const float4*)(delta_ws + ((size_t)(bh * NT + u)) * 64 + d4);
    }
    if (tid < NT) ltab[tid] = top[bh * NT + tid];

    const int e = ec * 64 + lane;
    const float* wrow = Wo + (size_t)e * EE + h * DD;
    float4 wo[16];
#pragma unroll
    for (int j = 0; j < 16; j++) wo[j] = *(const float4*)(wrow + j * 4);

    __syncthreads();

    float* obase = out + (size_t)b * LL * EE + e;
#pragma unroll
    for (int uu = 0; uu < 10; uu++) {
        const int u = wv * 10 + uu;
        float acc = 0.0f;
#pragma unroll
        for (int j = 0; j < 16; j++) {
            float4 dv = *(const float4*)&dl[u][j * 4];   // wave-uniform broadcast
            acc = fmaf(dv.x, wo[j].x, acc);
            acc = fmaf(dv.y, wo[j].y, acc);
            acc = fmaf(dv.z, wo[j].z, acc);
            acc = fmaf(dv.w, wo[j].w, acc);
        }
        atomicAdd(obase + (size_t)ltab[u] * EE, acc);    // 64-lane coalesced
    }
}

// ---------------------------------------------------------------------------
extern "C" void kernel_launch(void* const* d_in, const int* in_sizes, int n_in,
                              void* d_out, int out_size, void* d_ws, size_t ws_size,
                              hipStream_t stream)
{
    const float* query = (const float*)d_in[0];
    const float* key   = (const float*)d_in[1];
    const float* value = (const float*)d_in[2];
    const int*   idxs  = (const int*)d_in[3];
    const float* Wq = (const float*)d_in[4];
    const float* bq = (const float*)d_in[5];
    const float* Wk = (const float*)d_in[6];
    const float* bk = (const float*)d_in[7];
    const float* Wv = (const float*)d_in[8];
    const float* bv = (const float*)d_in[9];
    const float* Wo = (const float*)d_in[10];
    const float* bo = (const float*)d_in[11];
    float* out = (float*)d_out;

    // workspace layout (~60 MB)
    char* ws = (char*)d_ws;
    size_t off = 0;
    const size_t qkv_bytes = (size_t)BB * HH * LL * DD * sizeof(float); // 16 MB each
    float* q_ws = (float*)(ws + off); off += qkv_bytes;
    float* k_ws = (float*)(ws + off); off += qkv_bytes;
    float* v_ws = (float*)(ws + off); off += qkv_bytes;
    float* M_ws    = (float*)(ws + off); off += (size_t)BB * HH * LL * sizeof(float);
    int*   top_ws  = (int*)(ws + off);   off += (size_t)BB * HH * NT * sizeof(int);
    float* mean_ws = (float*)(ws + off); off += (size_t)BB * HH * DD * sizeof(float);
    float* vpart_ws = (float*)(ws + off); off += (size_t)BB * HH * MVC * DD * sizeof(float);
    float* mpart_ws = (float*)(ws + off); off += (size_t)BB * HH * NCH * NT * sizeof(float);
    float* lpart_ws = (float*)(ws + off); off += (size_t)BB * HH * NCH * NT * sizeof(float);
    float* accpart_ws = (float*)(ws + off); off += (size_t)BB * HH * NCH * NT * DD * sizeof(float);
    float* base_ws = (float*)(ws + off); off += (size_t)BB * EE * sizeof(float);
    float* delta_ws = (float*)(ws + off); off += (size_t)BB * HH * NT * DD * sizeof(float); // 320KB

    // Converted-W planes (3 MB) alias the head of accpart_ws (lifetimes
    // disjoint: wconv->proj vs pv->delta).
    unsigned short* wcv_ws = (unsigned short*)accpart_ws;

    // K0: pre-convert W to bf16 hi+mid planes
    wconv_kernel<<<384, 256, 0, stream>>>(Wq, Wk, Wv, wcv_ws);
    // K1: QKV projections (split-bf16 MFMA, 3 products, gload_lds B, prefetch)
    proj_kernel<<<768, 256, 0, stream>>>(query, key, value, wcv_ws, bq, bk, bv,
                                         q_ws, k_ws, v_ws);
    // K_A: fused sparsity measure + meanv stage 1
    measure_meanv_kernel<<<16384 + 512, 256, 0, stream>>>(q_ws, k_ws, v_ws, idxs,
                                                          M_ws, vpart_ws);
    // >>> INSTRUMENTATION (R12): duplicate launch — idempotent (deterministic
    // rewrite of M/vpart from unchanged inputs). Total-time delta vs the 262.9
    // baseline directly measures this kernel's cost, which the top-5 profile
    // window cannot see. Remove next round.
    measure_meanv_kernel<<<16384 + 512, 256, 0, stream>>>(q_ws, k_ws, v_ws, idxs,
                                                          M_ws, vpart_ws);
    // K_B: fused top-40 + meanv stage 2
    topk_comb_kernel<<<64, 64, 0, stream>>>(M_ws, vpart_ws, top_ws, mean_ws);
    // K5: split-K attention partials
    pv_kernel<<<BB * HH * NCH, 256, 0, stream>>>(q_ws, k_ws, v_ws, top_ws,
                                                 mpart_ws, lpart_ws, accpart_ws);
    // >>> INSTRUMENTATION (R12): duplicate launch — idempotent (deterministic
    // rewrite of mpart/lpart/accpart). Remove next round.
    pv_kernel<<<BB * HH * NCH, 256, 0, stream>>>(q_ws, k_ws, v_ws, top_ws,
                                                 mpart_ws, lpart_ws, accpart_ws);
    // K_C: fused delta precompute + base GEMV
    delta_base_kernel<<<320 + 512, 256, 0, stream>>>(accpart_ws, lpart_ws, mpart_ws,
                                                     mean_ws, Wo, bo,
                                                     delta_ws, base_ws);
    // K6b: broadcast base rows
    bcast_kernel<<<(BB * LL * EE) / (256 * 4), 256, 0, stream>>>(base_ws, out);
    // K6c: combine/correct scatter
    corr2_kernel<<<256, 256, 0, stream>>>(delta_ws, top_ws, Wo, out);
}

// Round 13
// 261.989 us; speedup vs baseline: 1.2397x; 1.2397x over previous
//
#include <hip/hip_runtime.h>
#include <hip/hip_bf16.h>
#include <math.h>

// Problem constants (fixed by reference)
constexpr int BB = 4;
constexpr int LL = 2048;
constexpr int EE = 512;
constexpr int HH = 8;
constexpr int DD = 64;
constexpr int UU = 40;    // sample count
constexpr int NT = 40;    // n_top
constexpr int NCH = 32;   // key chunks (64 keys each) for split-K attention
constexpr int CK = 64;    // keys per chunk
constexpr int MVC = 16;   // L-chunks for meanv stage 1 (128 rows each)
constexpr float NEG_INF = -3.0e38f;

typedef __attribute__((ext_vector_type(8))) short bf8_t;  // 8 bf16 (4 VGPR)
typedef __attribute__((ext_vector_type(4))) float f4_t;   // MFMA C/D frag

// ---------------------------------------------------------------------------
// split helpers: f32 = hi(RNE bf16) + mid(trunc bf16). Bit-identical math to
// the previous rounds (absmax must stay at 2.44e-4).
// ---------------------------------------------------------------------------
__device__ __forceinline__ void split2pair(float x0, float x1, uint& hp, uint& mp)
{
    uint xb0 = __float_as_uint(x0), xb1 = __float_as_uint(x1);
    uint hb0 = xb0 + 0x7fffu + ((xb0 >> 16) & 1u);
    uint hb1 = xb1 + 0x7fffu + ((xb1 >> 16) & 1u);
    hp = __builtin_amdgcn_perm(hb1, hb0, 0x07060302u);            // [h1.hi16|h0.hi16]
    float r0 = x0 - __uint_as_float(hb0 & 0xffff0000u);
    float r1 = x1 - __uint_as_float(hb1 & 0xffff0000u);
    mp = __builtin_amdgcn_perm(__float_as_uint(r1), __float_as_uint(r0), 0x07060302u);
}

__device__ __forceinline__ void gload16(const void* g, void* l)
{
    __builtin_amdgcn_global_load_lds(
        (const __attribute__((address_space(1))) unsigned int*)g,
        (__attribute__((address_space(3))) unsigned int*)l, 16, 0, 0);
}

__device__ __forceinline__ int swz(int row, int c)
{
    return row * 64 + (((c ^ row ^ (row >> 2)) & 3) << 4);
}

// ---------------------------------------------------------------------------
// K0: pre-convert Wq/Wk/Wv (f32 [512][512]) to bf16 hi+mid planes.
// ---------------------------------------------------------------------------
__global__ __launch_bounds__(256) void wconv_kernel(
    const float* __restrict__ Wq, const float* __restrict__ Wk,
    const float* __restrict__ Wv, unsigned short* __restrict__ wcv)
{
    const int gi  = blockIdx.x * 256 + threadIdx.x;   // 0..98303
    const int z   = gi >> 15;                         // 32768 threads per matrix
    const int off = (gi & 32767) * 8;
    const float* W = (z == 0) ? Wq : (z == 1 ? Wk : Wv);
    float x[8];
    *(float4*)(x)     = *(const float4*)(W + off);
    *(float4*)(x + 4) = *(const float4*)(W + off + 4);
    uint hp[4], mp[4];
#pragma unroll
    for (int p = 0; p < 4; p++) split2pair(x[2 * p], x[2 * p + 1], hp[p], mp[p]);
    unsigned short* Wh = wcv + (size_t)z * 524288;
    *(uint4*)(Wh + off)          = make_uint4(hp[0], hp[1], hp[2], hp[3]);
    *(uint4*)(Wh + 262144 + off) = make_uint4(mp[0], mp[1], mp[2], mp[3]);
}

// ---------------------------------------------------------------------------
// K1: fused QKV projection. 128x128x32 tile, 4 waves, 3-product split-bf16
// MFMA. R1 structure (measured 55-57us): 49KB LDS -> 3 blocks/CU. Do not
// re-raise LDS past ~53KB (R2's 64KB variant lost 7us to occupancy).
// ---------------------------------------------------------------------------
__global__ __launch_bounds__(256, 3) void proj_kernel(
    const float* __restrict__ Xq, const float* __restrict__ Xk, const float* __restrict__ Xv,
    const unsigned short* __restrict__ Wcv,
    const float* __restrict__ bq, const float* __restrict__ bk, const float* __restrict__ bv,
    float* __restrict__ Oq, float* __restrict__ Ok, float* __restrict__ Ov)
{
    // XCD-grouped decode: 768 = 8 xcd * 96; same (yi,zi) -> same xcd.
    const int bid = blockIdx.x;
    const int xg  = bid & 7;
    const int s   = bid >> 3;            // 0..95
    const int yz  = xg * 24 + (s >> 2);  // 0..191
    const int zi  = yz >> 6;             // 0..2
    const int yi  = yz & 63;
    const int m0  = yi * 128;
    const int n0  = (s & 3) * 128;

    const float* X; const float* bias; float* O;
    if (zi == 0)      { X = Xq; bias = bq; O = Oq; }
    else if (zi == 1) { X = Xk; bias = bk; O = Ok; }
    else              { X = Xv; bias = bv; O = Ov; }
    const unsigned short* Wh = Wcv + (size_t)zi * 524288;
    const unsigned short* Wm = Wh + 262144;

    __shared__ char ldsmem[49152];
    char* const LA = ldsmem;           // A tile: hi@0, mid@8192 (16KB)
    char* const LB = ldsmem + 16384;   // B tiles: 2 buffers x (hi 8KB + mid 8KB)

    const int tid  = threadIdx.x;
    const int lane = tid & 63;
    const int wave = tid >> 6;

    const int srow  = tid >> 1;
    const int shalf = tid & 1;
    const int w0 = swz(srow, shalf * 2);
    const int w1 = swz(srow, shalf * 2 + 1);
    const float* Aptr = X + (size_t)(m0 + srow) * EE + shalf * 16;

    const int r0 = tid >> 2;
    const int r1 = 64 + r0;
    const int c0 = (tid & 3) ^ ((r0 ^ (r0 >> 2)) & 3);
    const int c1 = (tid & 3) ^ ((r1 ^ (r1 >> 2)) & 3);
    const unsigned short* bh0 = Wh + (size_t)(n0 + r0) * EE + c0 * 8;
    const unsigned short* bh1 = Wh + (size_t)(n0 + r1) * EE + c1 * 8;
    const unsigned short* bm0 = Wm + (size_t)(n0 + r0) * EE + c0 * 8;
    const unsigned short* bm1 = Wm + (size_t)(n0 + r1) * EE + c1 * 8;
    const int ldst = tid * 16;         // linear dest: wave-uniform base + lane*16

    const int rxor = ((((lane >> 4) ^ lane ^ (lane >> 2)) & 3) << 4);
    const int arow = (wave >> 1) * 64 + (lane & 15);
    const int brow = (wave & 1) * 64 + (lane & 15);

    f4_t acc[4][4];
#pragma unroll
    for (int i = 0; i < 4; i++)
#pragma unroll
        for (int j = 0; j < 4; j++) acc[i][j] = (f4_t)0.0f;

    // prologue: A regs + B tile for kt=0 (into buffer 0)
    float fa[16];
#pragma unroll
    for (int q = 0; q < 4; q++)
        *(float4*)(fa + q * 4) = *(const float4*)(Aptr + q * 4);
    gload16(bh0, LB + ldst);
    gload16(bh1, LB + 4096 + ldst);
    gload16(bm0, LB + 8192 + ldst);
    gload16(bm1, LB + 12288 + ldst);

    int parity = 0;
#pragma unroll 2
    for (int kt = 0; kt < EE; kt += 32) {
        uint ahu[8], amu[8];
#pragma unroll
        for (int p = 0; p < 8; p++)
            split2pair(fa[2 * p], fa[2 * p + 1], ahu[p], amu[p]);

        __syncthreads();   // WAR: previous iteration's A-frag reads done
        *(uint4*)(LA +    0 + w0) = make_uint4(ahu[0], ahu[1], ahu[2], ahu[3]);
        *(uint4*)(LA +    0 + w1) = make_uint4(ahu[4], ahu[5], ahu[6], ahu[7]);
        *(uint4*)(LA + 8192 + w0) = make_uint4(amu[0], amu[1], amu[2], amu[3]);
        *(uint4*)(LA + 8192 + w1) = make_uint4(amu[4], amu[5], amu[6], amu[7]);
        __syncthreads();   // A visible; vmcnt(0) drain completes B(kt)

        if (kt + 32 < EE) {
            const int kn = kt + 32;
#pragma unroll
            for (int q = 0; q < 4; q++)
                *(float4*)(fa + q * 4) = *(const float4*)(Aptr + kn + q * 4);
            char* Bn = LB + (parity ^ 1) * 16384;
            gload16(bh0 + kn, Bn + ldst);
            gload16(bh1 + kn, Bn + 4096 + ldst);
            gload16(bm0 + kn, Bn + 8192 + ldst);
            gload16(bm1 + kn, Bn + 12288 + ldst);
        }

        char* const Bb = LB + parity * 16384;
        bf8_t af[4][2];
#pragma unroll
        for (int i = 0; i < 4; i++) {
            const int ro = (arow + i * 16) * 64 + rxor;
            af[i][0] = *(const bf8_t*)(LA +    0 + ro);
            af[i][1] = *(const bf8_t*)(LA + 8192 + ro);
        }
#pragma unroll
        for (int j = 0; j < 4; j++) {
            const int ro = (brow + j * 16) * 64 + rxor;
            bf8_t bh_ = *(const bf8_t*)(Bb +    0 + ro);
            bf8_t bm_ = *(const bf8_t*)(Bb + 8192 + ro);
#pragma unroll
            for (int i = 0; i < 4; i++) {
                f4_t c = acc[i][j];
                c = __builtin_amdgcn_mfma_f32_16x16x32_bf16(af[i][0], bh_, c, 0, 0, 0); // hh
                c = __builtin_amdgcn_mfma_f32_16x16x32_bf16(af[i][0], bm_, c, 0, 0, 0); // hm
                c = __builtin_amdgcn_mfma_f32_16x16x32_bf16(af[i][1], bh_, c, 0, 0, 0); // mh
                acc[i][j] = c;
            }
        }
        parity ^= 1;
    }

#pragma unroll
    for (int j = 0; j < 4; j++) {
        const int n  = n0 + (wave & 1) * 64 + j * 16 + (lane & 15);
        const float bn = bias[n];
        const int h_ = n >> 6, d_ = n & 63;
#pragma unroll
        for (int i = 0; i < 4; i++) {
            const int mb = m0 + (wave >> 1) * 64 + i * 16 + ((lane >> 4) << 2);
#pragma unroll
            for (int r = 0; r < 4; r++) {
                const int m  = mb + r;
                const int b_ = m >> 11;
                const int l_ = m & (LL - 1);
                O[(((size_t)(b_ * HH + h_) * LL + l_) << 6) + d_] = acc[i][j][r] + bn;
            }
        }
    }
}

// ---------------------------------------------------------------------------
// K_A: FUSED measure + meanv_part (R9 decode — best measured config).
// R12 instrumentation: measure+meanv ~= 28us — at ~23 TB/s effective for the
// 655MB gather, i.e. near the L2/L3-BW bound. This explains why all three
// locality permutations (R4/R6/R10) were null: volume, not placement, is
// the cost. Do not retry ordering tricks here.
// Blocks 0..16383: measure. Blocks 16384..16895: meanv stage 1.
// ---------------------------------------------------------------------------
__global__ __launch_bounds__(256) void measure_meanv_kernel(
    const float* __restrict__ q, const float* __restrict__ k,
    const float* __restrict__ v, const int* __restrict__ idx_sample,
    float* __restrict__ M, float* __restrict__ vpart)
{
    __shared__ float red[4][DD];

    if (blockIdx.x < 16384) {
        const int xg = blockIdx.x & 7;
        const int sb = blockIdx.x >> 3;      // 0..2047
        const int bh = xg * 4 + (sb & 3);
        const int lc = sb >> 2;              // 0..511
        int lane = threadIdx.x & 63;
        int wv   = threadIdx.x >> 6;
        int l    = lc * 4 + wv;
        int s8   = lane >> 3;   // sample slot 0..7
        int c    = lane & 7;    // d-chunk 0..7

        const float* qrow = q + ((size_t)bh * LL + l) * DD + c * 8;
        float4 q0 = *(const float4*)(qrow);
        float4 q1 = *(const float4*)(qrow + 4);

        const float* kbase = k + (size_t)bh * LL * DD;
        const int*   irow  = idx_sample + l * UU;

        float mx = NEG_INF, sum = 0.0f;
#pragma unroll
        for (int it = 0; it < UU; it += 8) {
            int ki = irow[it + s8];
            const float* krow = kbase + (size_t)ki * DD + c * 8;
            float4 k0 = *(const float4*)(krow);
            float4 k1 = *(const float4*)(krow + 4);
            float p = q0.x*k0.x + q0.y*k0.y + q0.z*k0.z + q0.w*k0.w
                    + q1.x*k1.x + q1.y*k1.y + q1.z*k1.z + q1.w*k1.w;
            p += __shfl_xor(p, 1, 64);
            p += __shfl_xor(p, 2, 64);
            p += __shfl_xor(p, 4, 64);
            mx = fmaxf(mx, p);
            sum += p;
        }
        mx  = fmaxf(mx, __shfl_xor(mx, 8, 64));
        sum += __shfl_xor(sum, 8, 64);
        mx  = fmaxf(mx, __shfl_xor(mx, 16, 64));
        sum += __shfl_xor(sum, 16, 64);
        mx  = fmaxf(mx, __shfl_xor(mx, 32, 64));
        sum += __shfl_xor(sum, 32, 64);

        if (lane == 0) M[bh * LL + l] = mx - sum * (1.0f / (float)LL);
    } else {
        const int bid2  = blockIdx.x - 16384;   // 0..511
        const int bh    = bid2 & 31;
        const int chunk = bid2 >> 5;
        const int d  = threadIdx.x & 63;
        const int wv = threadIdx.x >> 6;
        const float* base = v + ((size_t)bh * LL + chunk * 128 + wv * 32) * DD + d;
        float acc = 0.0f;
#pragma unroll
        for (int i = 0; i < 32; i++) acc += base[i * DD];
        red[wv][d] = acc;
        __syncthreads();
        if (wv == 0)
            vpart[(size_t)(chunk * 32 + bh) * DD + d]
                = red[0][d] + red[1][d] + red[2][d] + red[3][d];
    }
}

// ---------------------------------------------------------------------------
// K_B: FUSED topk + meanv_comb. Blocks 0..31: top-40. Blocks 32..63: comb.
// R13 topk tweaks (selection outcomes bit-identical):
//  - lmax rebuild: 5-level tree (dep ~30cy) instead of 32-step linear chain
//    (~190cy). Max is associative -> exact.
//  - extraction match: low-32 compare (the packed index uniquely identifies
//    the element) instead of full-64 compare.
// ---------------------------------------------------------------------------
__global__ __launch_bounds__(64) void topk_comb_kernel(const float* __restrict__ M,
                                                       const float* __restrict__ vpart,
                                                       int* __restrict__ top,
                                                       float* __restrict__ mean_v)
{
    if (blockIdx.x < 32) {
        const int bh   = blockIdx.x;
        const int lane = threadIdx.x;

        unsigned long long keys[32];
#pragma unroll
        for (int i = 0; i < 32; i++) {
            int idx = i * 64 + lane;
            uint u  = __float_as_uint(M[bh * LL + idx]);
            uint sv = (u & 0x80000000u) ? ~u : (u | 0x80000000u);
            keys[i] = ((unsigned long long)sv << 32) | (uint)(LL - 1 - idx);
        }

        unsigned long long t[16];
        auto tree_max = [&]() -> unsigned long long {
#pragma unroll
            for (int i = 0; i < 16; i++)
                t[i] = (keys[2 * i] > keys[2 * i + 1]) ? keys[2 * i] : keys[2 * i + 1];
#pragma unroll
            for (int s_ = 8; s_ >= 1; s_ >>= 1)
#pragma unroll
                for (int i = 0; i < 16; i++)
                    if (i < s_) t[i] = (t[i] > t[i + s_]) ? t[i] : t[i + s_];
            return t[0];
        };

        unsigned long long lmax = tree_max();

        for (int it = 0; it < NT; it++) {
            unsigned long long g = lmax;
#pragma unroll
            for (int off = 1; off < 64; off <<= 1) {
                unsigned long long o = __shfl_xor(g, off, 64);
                g = (o > g) ? o : g;
            }
            if (lane == 0) top[bh * NT + it] = LL - 1 - (int)(g & 0xffffffffu);
            const uint glo = (uint)g;
#pragma unroll
            for (int i = 0; i < 32; i++)
                if ((uint)keys[i] == glo) keys[i] = 0ull;
            lmax = tree_max();
        }
    } else {
        const int bh = blockIdx.x - 32;
        const int d  = threadIdx.x;
        float s = 0.0f;
#pragma unroll
        for (int c = 0; c < MVC; c++) s += vpart[(size_t)(c * 32 + bh) * DD + d];
        mean_v[bh * DD + d] = s * (1.0f / (float)LL);
    }
}

// ---------------------------------------------------------------------------
// K5: flash-style split-K attention partials (R8/R9 body — measured ~28us in
// R12 instrumentation, matching the LDS+VALU pipe model; near its floor for
// this structure).
// ---------------------------------------------------------------------------
__global__ __launch_bounds__(256) void pv_kernel(const float* __restrict__ q,
                                                 const float* __restrict__ k,
                                                 const float* __restrict__ v,
                                                 const int* __restrict__ top,
                                                 float* __restrict__ mpart,
                                                 float* __restrict__ lpart,
                                                 float* __restrict__ accpart)
{
    const int bh    = blockIdx.x & 31;
    const int chunk = blockIdx.x >> 5;
    const int tid   = threadIdx.x;
    const int lane  = tid & 63, wv = tid >> 6;

    __shared__ alignas(16) float qs[NT][DD];        // 10240 B
    __shared__ alignas(16) float sc[NT][CK + 4];    // 10880 B (row stride 272B = 16-mult)

    for (int i = tid; i < NT * DD / 4; i += 256) {
        int u  = i >> 4;
        int d4 = (i & 15) * 4;
        int l  = top[bh * NT + u];
        *(float4*)&qs[u][d4] = *(const float4*)(q + ((size_t)bh * LL + l) * DD + d4);
    }
    __syncthreads();

    {
        const int key  = tid >> 2;
        const int dseg = tid & 3;
        const float* krow = k + ((size_t)bh * LL + chunk * CK + key) * DD + dseg * 16;
        float4 k0 = *(const float4*)(krow);
        float4 k1 = *(const float4*)(krow + 4);
        float4 k2 = *(const float4*)(krow + 8);
        float4 k3 = *(const float4*)(krow + 12);
#pragma unroll 8
        for (int u = 0; u < NT; u++) {
            const float* qrow = &qs[u][dseg * 16];
            float4 q0 = *(const float4*)(qrow);
            float4 q1 = *(const float4*)(qrow + 4);
            float4 q2 = *(const float4*)(qrow + 8);
            float4 q3 = *(const float4*)(qrow + 12);
            float p = k0.x*q0.x + k0.y*q0.y + k0.z*q0.z + k0.w*q0.w
                    + k1.x*q1.x + k1.y*q1.y + k1.z*q1.z + k1.w*q1.w
                    + k2.x*q2.x + k2.y*q2.y + k2.z*q2.z + k2.w*q2.w
                    + k3.x*q3.x + k3.y*q3.y + k3.z*q3.z + k3.w*q3.w;
            p += __shfl_xor(p, 1, 64);
            p += __shfl_xor(p, 2, 64);
            if (dseg == 0) sc[u][key] = p;
        }
    }
    __syncthreads();

#pragma unroll
    for (int i = 0; i < 10; i++) {
        const int u = wv * 10 + i;
        float val = sc[u][lane];
        float mx = val;
        mx = fmaxf(mx, __shfl_xor(mx, 1, 64));
        mx = fmaxf(mx, __shfl_xor(mx, 2, 64));
        mx = fmaxf(mx, __shfl_xor(mx, 4, 64));
        mx = fmaxf(mx, __shfl_xor(mx, 8, 64));
        mx = fmaxf(mx, __shfl_xor(mx, 16, 64));
        mx = fmaxf(mx, __shfl_xor(mx, 32, 64));
        float e = __expf(val - mx);
        sc[u][lane] = e;
        float s = e;
        s += __shfl_xor(s, 1, 64);
        s += __shfl_xor(s, 2, 64);
        s += __shfl_xor(s, 4, 64);
        s += __shfl_xor(s, 8, 64);
        s += __shfl_xor(s, 16, 64);
        s += __shfl_xor(s, 32, 64);
        if (lane == 0) {
            mpart[(bh * NCH + chunk) * NT + u] = mx;
            lpart[(bh * NCH + chunk) * NT + u] = s;
        }
    }
    __syncthreads();

    {
        float pacc[10];
#pragma unroll
        for (int i = 0; i < 10; i++) pacc[i] = 0.0f;
        const float* vbase = v + ((size_t)bh * LL + chunk * CK) * DD + lane;
#pragma unroll 4
        for (int t = 0; t < CK; t += 4) {
            float v0 = vbase[(size_t)(t + 0) * DD];
            float v1 = vbase[(size_t)(t + 1) * DD];
            float v2 = vbase[(size_t)(t + 2) * DD];
            float v3 = vbase[(size_t)(t + 3) * DD];
#pragma unroll
            for (int i = 0; i < 10; i++) {
                float4 s = *(const float4*)&sc[wv * 10 + i][t];   // wave-uniform b128
                pacc[i] = fmaf(s.x, v0, pacc[i]);
                pacc[i] = fmaf(s.y, v1, pacc[i]);
                pacc[i] = fmaf(s.z, v2, pacc[i]);
                pacc[i] = fmaf(s.w, v3, pacc[i]);
            }
        }
#pragma unroll
        for (int i = 0; i < 10; i++) {
            const int u = wv * 10 + i;
            accpart[(((size_t)(bh * NCH + chunk)) * NT + u) * 64 + lane] = pacc[i];
        }
    }
}

// ---------------------------------------------------------------------------
// K_C: FUSED delta + base. Blocks 0..319: delta (320x256thr, wave=u).
// Blocks 320..831: base GEMV.
// ---------------------------------------------------------------------------
__global__ __launch_bounds__(256) void delta_base_kernel(
    const float* __restrict__ accpart, const float* __restrict__ lpart,
    const float* __restrict__ mpart, const float* __restrict__ mean_v,
    const float* __restrict__ Wo, const float* __restrict__ bo,
    float* __restrict__ delta_ws, float* __restrict__ base)
{
    if (blockIdx.x < 320) {
        const int bh = blockIdx.x / 10;
        const int ug = blockIdx.x % 10;
        const int wv = threadIdx.x >> 6;
        const int u  = ug * 4 + wv;
        const int d  = threadIdx.x & 63;
        const int bhu = bh * NT + u;

        const float* mp = mpart + (size_t)bh * NCH * NT + u;
        const float* lp = lpart + (size_t)bh * NCH * NT + u;
        const float* ap = accpart + ((size_t)bh * NCH * NT + u) * 64 + d;

        float m = NEG_INF;
#pragma unroll
        for (int c = 0; c < NCH; c++) m = fmaxf(m, mp[c * NT]);
        float den = 0.0f, num = 0.0f;
#pragma unroll
        for (int c = 0; c < NCH; c++) {
            float f = __expf(mp[c * NT] - m);
            den += lp[c * NT] * f;
            num += ap[(size_t)c * NT * 64] * f;
        }
        delta_ws[(size_t)bhu * 64 + d] = num / den - mean_v[bh * DD + d];
    } else {
        const int bid2 = blockIdx.x - 320;
        int lane = threadIdx.x & 63, wv = threadIdx.x >> 6;
        int be = bid2 * 4 + wv;
        int b  = be >> 9;
        int e  = be & (EE - 1);
        const float* mrow = mean_v + b * EE;
        const float* wrow = Wo + (size_t)e * EE;
        float acc = 0.0f;
#pragma unroll
        for (int j = 0; j < 8; j++) acc += mrow[lane + j * 64] * wrow[lane + j * 64];
#pragma unroll
        for (int off = 32; off > 0; off >>= 1) acc += __shfl_down(acc, off, 64);
        if (lane == 0) base[be] = acc + bo[e];
    }
}

// ---------------------------------------------------------------------------
// K6b: broadcast base row to all l
// ---------------------------------------------------------------------------
__global__ __launch_bounds__(256) void bcast_kernel(const float* __restrict__ base,
                                                    float* __restrict__ out)
{
    size_t fi = ((size_t)blockIdx.x * 256 + threadIdx.x) * 4;
    int b  = (int)(fi >> 20);
    int e4 = (int)(fi & (EE - 1));
    float4 val = *(const float4*)(base + b * EE + e4);
    *(float4*)(out + fi) = val;
}

// ---------------------------------------------------------------------------
// K6c-2: correction GEMV + scatter. 256 blocks = (ec 0..7) x (bh 0..31).
// ---------------------------------------------------------------------------
__global__ __launch_bounds__(256) void corr2_kernel(const float* __restrict__ delta_ws,
                                                    const int* __restrict__ top,
                                                    const float* __restrict__ Wo,
                                                    float* __restrict__ out)
{
    const int bh  = blockIdx.x & 31;
    const int ec  = blockIdx.x >> 5;     // 0..7
    const int h   = bh & (HH - 1);
    const int b   = bh >> 3;
    const int tid = threadIdx.x;
    const int lane = tid & 63;
    const int wv   = tid >> 6;

    __shared__ alignas(16) float dl[NT][DD];   // 10240 B, b128-aligned rows
    __shared__ int ltab[NT];

    for (int i = tid; i < NT * DD / 4; i += 256) {
        const int u  = i >> 4;
        const int d4 = (i & 15) * 4;
        *(float4*)&dl[u][d4] = *(const float4*)(delta_ws + ((size_t)(bh * NT + u)) * 64 + d4);
    }
    if (tid < NT) ltab[tid] = top[bh * NT + tid];

    const int e = ec * 64 + lane;
    const float* wrow = Wo + (size_t)e * EE + h * DD;
    float4 wo[16];
#pragma unroll
    for (int j = 0; j < 16; j++) wo[j] = *(const float4*)(wrow + j * 4);

    __syncthreads();

    float* obase = out + (size_t)b * LL * EE + e;
#pragma unroll
    for (int uu = 0; uu < 10; uu++) {
        const int u = wv * 10 + uu;
        float acc = 0.0f;
#pragma unroll
        for (int j = 0; j < 16; j++) {
            float4 dv = *(const float4*)&dl[u][j * 4];   // wave-uniform broadcast
            acc = fmaf(dv.x, wo[j].x, acc);
            acc = fmaf(dv.y, wo[j].y, acc);
            acc = fmaf(dv.z, wo[j].z, acc);
            acc = fmaf(dv.w, wo[j].w, acc);
        }
        atomicAdd(obase + (size_t)ltab[u] * EE, acc);    // 64-lane coalesced
    }
}

// ---------------------------------------------------------------------------
extern "C" void kernel_launch(void* const* d_in, const int* in_sizes, int n_in,
                              void* d_out, int out_size, void* d_ws, size_t ws_size,
                              hipStream_t stream)
{
    const float* query = (const float*)d_in[0];
    const float* key   = (const float*)d_in[1];
    const float* value = (const float*)d_in[2];
    const int*   idxs  = (const int*)d_in[3];
    const float* Wq = (const float*)d_in[4];
    const float* bq = (const float*)d_in[5];
    const float* Wk = (const float*)d_in[6];
    const float* bk = (const float*)d_in[7];
    const float* Wv = (const float*)d_in[8];
    const float* bv = (const float*)d_in[9];
    const float* Wo = (const float*)d_in[10];
    const float* bo = (const float*)d_in[11];
    float* out = (float*)d_out;

    // workspace layout (~60 MB)
    char* ws = (char*)d_ws;
    size_t off = 0;
    const size_t qkv_bytes = (size_t)BB * HH * LL * DD * sizeof(float); // 16 MB each
    float* q_ws = (float*)(ws + off); off += qkv_bytes;
    float* k_ws = (float*)(ws + off); off += qkv_bytes;
    float* v_ws = (float*)(ws + off); off += qkv_bytes;
    float* M_ws    = (float*)(ws + off); off += (size_t)BB * HH * LL * sizeof(float);
    int*   top_ws  = (int*)(ws + off);   off += (size_t)BB * HH * NT * sizeof(int);
    float* mean_ws = (float*)(ws + off); off += (size_t)BB * HH * DD * sizeof(float);
    float* vpart_ws = (float*)(ws + off); off += (size_t)BB * HH * MVC * DD * sizeof(float);
    float* mpart_ws = (float*)(ws + off); off += (size_t)BB * HH * NCH * NT * sizeof(float);
    float* lpart_ws = (float*)(ws + off); off += (size_t)BB * HH * NCH * NT * sizeof(float);
    float* accpart_ws = (float*)(ws + off); off += (size_t)BB * HH * NCH * NT * DD * sizeof(float);
    float* base_ws = (float*)(ws + off); off += (size_t)BB * EE * sizeof(float);
    float* delta_ws = (float*)(ws + off); off += (size_t)BB * HH * NT * DD * sizeof(float); // 320KB

    // Converted-W planes (3 MB) alias the head of accpart_ws (lifetimes
    // disjoint: wconv->proj vs pv->delta).
    unsigned short* wcv_ws = (unsigned short*)accpart_ws;

    // K0: pre-convert W to bf16 hi+mid planes
    wconv_kernel<<<384, 256, 0, stream>>>(Wq, Wk, Wv, wcv_ws);
    // K1: QKV projections (split-bf16 MFMA, 3 products, gload_lds B, prefetch)
    proj_kernel<<<768, 256, 0, stream>>>(query, key, value, wcv_ws, bq, bk, bv,
                                         q_ws, k_ws, v_ws);
    // K_A: fused sparsity measure + meanv stage 1 (~28us, near L2/L3-BW bound)
    measure_meanv_kernel<<<16384 + 512, 256, 0, stream>>>(q_ws, k_ws, v_ws, idxs,
                                                          M_ws, vpart_ws);
    // K_B: fused top-40 (tree-rebuild) + meanv stage 2
    topk_comb_kernel<<<64, 64, 0, stream>>>(M_ws, vpart_ws, top_ws, mean_ws);
    // K5: split-K attention partials (~28us measured)
    pv_kernel<<<BB * HH * NCH, 256, 0, stream>>>(q_ws, k_ws, v_ws, top_ws,
                                                 mpart_ws, lpart_ws, accpart_ws);
    // K_C: fused delta precompute + base GEMV
    delta_base_kernel<<<320 + 512, 256, 0, stream>>>(accpart_ws, lpart_ws, mpart_ws,
                                                     mean_ws, Wo, bo,
                                                     delta_ws, base_ws);
    // K6b: broadcast base rows
    bcast_kernel<<<(BB * LL * EE) / (256 * 4), 256, 0, stream>>>(base_ws, out);
    // K6c: combine/correct scatter
    corr2_kernel<<<256, 256, 0, stream>>>(delta_ws, top_ws, Wo, out);
}